// Round 8
// baseline (531.522 us; speedup 1.0000x reference)
//
#include <hip/hip_runtime.h>
#include <math.h>

// Problem constants (from reference)
#define TT 10
#define SS 10
#define RR 2000
#define KK 100
#define OO 500
#define PP (TT*SS*RR)        // 200000 particles
#define NT16 12500           // 16-row tiles
#define NT 7                 // 7 N-tiles of 16 cols -> 112 padded assemblages
#define WAVES 16             // 1024-thread block, 1 block/CU -> 16 waves/CU
#define BLOCKT (WAVES*64)
#define NBLK 256
#define EPSF 1e-6f

typedef float        f32x4  __attribute__((ext_vector_type(4)));
typedef unsigned int u32x4  __attribute__((ext_vector_type(4)));
typedef __bf16       bf16x8 __attribute__((ext_vector_type(8)));

union BFU { bf16x8 v; u32x4 q; };

// ---------------------------------------------------------------------------
// Prep: theta = softmax -> out[1..50001); beta copy -> out[50001..);
// out[0] = 0; tile counter (d_ws) = 0.
// ---------------------------------------------------------------------------
__global__ __launch_bounds__(64) void mcspace_prep(
    const float* __restrict__ theta_params,
    const float* __restrict__ beta,
    float* __restrict__ out,
    unsigned* __restrict__ cnt)
{
    const int b  = blockIdx.x;
    const int ln = threadIdx.x;
    if (b < KK) {
        const float* tp = theta_params + b * OO;
        float x[8];
        #pragma unroll
        for (int j = 0; j < 8; ++j) {
            int o = ln + 64 * j;
            x[j] = (o < OO) ? tp[o] : -INFINITY;
        }
        float mx = x[0];
        #pragma unroll
        for (int j = 1; j < 8; ++j) mx = fmaxf(mx, x[j]);
        #pragma unroll
        for (int w = 1; w < 64; w <<= 1) mx = fmaxf(mx, __shfl_xor(mx, w));
        float e[8], sm = 0.f;
        #pragma unroll
        for (int j = 0; j < 8; ++j) { e[j] = __expf(x[j] - mx); sm += e[j]; }
        #pragma unroll
        for (int w = 1; w < 64; w <<= 1) sm += __shfl_xor(sm, w);
        const float inv = 1.f / sm;
        float* to = out + 1 + b * OO;
        #pragma unroll
        for (int j = 0; j < 8; ++j) {
            int o = ln + 64 * j;
            if (o < OO) to[o] = e[j] * inv;
        }
    } else {
        int idx = (b - KK) * 64 + ln;
        if (idx < KK * TT * SS) out[1 + KK * OO + idx] = beta[idx];
        if (b == KK && ln == 0) { out[0] = 0.f; cnt[0] = 0u; }
    }
}

// ---------------------------------------------------------------------------
// Main: R1 structure (B in LDS, 16 waves/CU, direct A gather) + dynamic
// pipelined tile counter + depth-2 A prefetch + vectorized remainder.
// ---------------------------------------------------------------------------
__global__ __launch_bounds__(BLOCKT) void mcspace_main(
    const float* __restrict__ counts,
    const float* __restrict__ theta_params,
    const float* __restrict__ beta,
    unsigned* __restrict__ cnt,
    float* __restrict__ out)
{
    __shared__ u32x4 ldsB[7168];   // logtheta bf16 [112][512], swizzled rows (112 KB)
    __shared__ float red[WAVES];
    char* ldsBytes = (char*)&ldsB[0];

    const int tid = threadIdx.x;
    const int wv  = tid >> 6;     // wave id 0..15
    const int ln  = tid & 63;
    const int lo  = ln & 15;
    const int g   = ln >> 4;
    const int kb  = g * 8;

    // ---- build logtheta bf16 [112][512] in LDS (each wave does 7 rows) ----
    for (int it = 0; it < 7; ++it) {
        const int row = wv + 16 * it;          // 0..111 (bijective)
        BFU w8; w8.q = (u32x4){0u, 0u, 0u, 0u};
        if (row < KK) {
            const float* tp = theta_params + row * OO;
            float x[8];
            #pragma unroll
            for (int j = 0; j < 8; ++j) {
                int o = ln * 8 + j;
                x[j] = (o < OO) ? tp[o] : -INFINITY;
            }
            float mx = x[0];
            #pragma unroll
            for (int j = 1; j < 8; ++j) mx = fmaxf(mx, x[j]);
            #pragma unroll
            for (int w = 1; w < 64; w <<= 1) mx = fmaxf(mx, __shfl_xor(mx, w));
            float e[8], sm = 0.f;
            #pragma unroll
            for (int j = 0; j < 8; ++j) { e[j] = __expf(x[j] - mx); sm += e[j]; }
            #pragma unroll
            for (int w = 1; w < 64; w <<= 1) sm += __shfl_xor(sm, w);
            const float inv = 1.f / sm;
            #pragma unroll
            for (int j = 0; j < 8; ++j)
                w8.v[j] = (__bf16)__logf(e[j] * inv + EPSF);  // log(theta + EPS)
        }
        *(u32x4*)(ldsBytes + (row * 1024 + ((ln * 16) ^ ((row & 7) << 4)))) = w8.q;
    }
    __syncthreads();

    float wacc = 0.f;

    // first tile id
    unsigned t = 0;
    if (ln == 0) t = atomicAdd(cnt, 1u);
    t = (unsigned)__shfl((int)t, 0);

    while (t < NT16) {
        // issue NEXT tile-id fetch now; consume after this tile's compute
        unsigned tn = 0;
        if (ln == 0) tn = atomicAdd(cnt, 1u);

        const int ts = (int)t / 125;         // 125 tiles per (t,s)
        const float* rp = counts + (long)(t * 16 + lo) * OO;

        // beta for this tile (in flight during k-loop)
        float bet[NT];
        #pragma unroll
        for (int nt = 0; nt < NT; ++nt) {
            int j = nt * 16 + lo;
            bet[nt] = (j < KK) ? beta[j * (TT * SS) + ts] : 0.f;
        }

        f32x4 acc[NT];
        #pragma unroll
        for (int nt = 0; nt < NT; ++nt) acc[nt] = (f32x4){0.f, 0.f, 0.f, 0.f};

        // depth-2 prefetch rotation
        f32x4 c0 = *(const f32x4*)(rp + kb);
        f32x4 c1 = *(const f32x4*)(rp + kb + 4);
        f32x4 n0 = *(const f32x4*)(rp + 32 + kb);
        f32x4 n1 = *(const f32x4*)(rp + 32 + kb + 4);
        f32x4 r0 = (f32x4){0.f, 0.f, 0.f, 0.f};
        f32x4 r1 = (f32x4){0.f, 0.f, 0.f, 0.f};

        #pragma unroll
        for (int ko = 0; ko < 15; ++ko) {
            BFU a;
            #pragma unroll
            for (int j = 0; j < 4; ++j) {
                a.v[j]     = (__bf16)c0[j];
                a.v[4 + j] = (__bf16)c1[j];
            }
            if (ko < 13) {
                c0 = n0; c1 = n1;
                n0 = *(const f32x4*)(rp + (ko + 2) * 32 + kb);
                n1 = *(const f32x4*)(rp + (ko + 2) * 32 + kb + 4);
            } else if (ko == 13) {
                c0 = n0; c1 = n1;
                // remainder k=480..499: per-group f32x4s, compile-time masked
                if (kb < 20)     r0 = *(const f32x4*)(rp + 480 + kb);
                if (kb + 4 < 20) r1 = *(const f32x4*)(rp + 484 + kb);
            }
            const int bb = ko * 64 + g * 16;
            #pragma unroll
            for (int nt = 0; nt < NT; ++nt) {
                const int row = nt * 16 + lo;
                BFU bv;
                bv.q = *(const u32x4*)(ldsBytes + (row * 1024 + (bb ^ ((row & 7) << 4))));
                acc[nt] = __builtin_amdgcn_mfma_f32_16x16x32_bf16(a.v, bv.v, acc[nt], 0, 0, 0);
            }
        }
        // remainder K-step (k = 480..511; cols >= 500 are zero by construction)
        {
            BFU a;
            #pragma unroll
            for (int j = 0; j < 4; ++j) {
                a.v[j]     = (__bf16)r0[j];
                a.v[4 + j] = (__bf16)r1[j];
            }
            const int bb = 15 * 64 + g * 16;
            #pragma unroll
            for (int nt = 0; nt < NT; ++nt) {
                const int row = nt * 16 + lo;
                BFU bv;
                bv.q = *(const u32x4*)(ldsBytes + (row * 1024 + (bb ^ ((row & 7) << 4))));
                acc[nt] = __builtin_amdgcn_mfma_f32_16x16x32_bf16(a.v, bv.v, acc[nt], 0, 0, 0);
            }
        }

        // ---- beta-weighted logsumexp (in-register, R1-verified layout) ----
        float mrow[4] = {-INFINITY, -INFINITY, -INFINITY, -INFINITY};
        #pragma unroll
        for (int nt = 0; nt < NT; ++nt) {
            const bool valid = (nt * 16 + lo) < KK;
            #pragma unroll
            for (int r = 0; r < 4; ++r)
                mrow[r] = fmaxf(mrow[r], valid ? acc[nt][r] : -INFINITY);
        }
        #pragma unroll
        for (int w = 1; w < 16; w <<= 1) {
            #pragma unroll
            for (int r = 0; r < 4; ++r)
                mrow[r] = fmaxf(mrow[r], __shfl_xor(mrow[r], w));
        }
        float srow[4] = {0.f, 0.f, 0.f, 0.f};
        #pragma unroll
        for (int nt = 0; nt < NT; ++nt) {
            const bool valid = (nt * 16 + lo) < KK;
            #pragma unroll
            for (int r = 0; r < 4; ++r)
                srow[r] += bet[nt] * __expf(valid ? (acc[nt][r] - mrow[r]) : -INFINITY);
        }
        #pragma unroll
        for (int w = 1; w < 16; w <<= 1) {
            #pragma unroll
            for (int r = 0; r < 4; ++r)
                srow[r] += __shfl_xor(srow[r], w);
        }
        if (lo == 0) {
            #pragma unroll
            for (int r = 0; r < 4; ++r)
                wacc += mrow[r] + __logf(srow[r] + EPSF);
        }

        // consume pipelined tile id
        t = (unsigned)__shfl((int)tn, 0);
    }

    // ---- deterministic block reduction, one atomic per block ----
    #pragma unroll
    for (int w = 1; w < 64; w <<= 1) wacc += __shfl_xor(wacc, w);
    if (ln == 0) red[wv] = wacc;
    __syncthreads();
    if (tid == 0) {
        float s = 0.f;
        #pragma unroll
        for (int i = 0; i < WAVES; ++i) s += red[i];
        atomicAdd(out, -s);   // elbo_loss = -loglik
    }
}

extern "C" void kernel_launch(void* const* d_in, const int* in_sizes, int n_in,
                              void* d_out, int out_size, void* d_ws, size_t ws_size,
                              hipStream_t stream)
{
    (void)in_sizes; (void)n_in; (void)ws_size; (void)out_size;
    const float* counts       = (const float*)d_in[0];
    const float* theta_params = (const float*)d_in[1];
    const float* beta         = (const float*)d_in[2];
    float* out    = (float*)d_out;
    unsigned* cnt = (unsigned*)d_ws;      // dynamic tile counter (zeroed by prep)

    // prep: 100 softmax rows + 157 beta-copy blocks (one wave each)
    mcspace_prep<<<dim3(KK + (KK * TT * SS + 63) / 64), dim3(64), 0, stream>>>(
        theta_params, beta, out, cnt);
    // main: 256 blocks x 16 waves (1 block/CU), dynamic pipelined tiles
    mcspace_main<<<dim3(NBLK), dim3(BLOCKT), 0, stream>>>(
        counts, theta_params, beta, cnt, out);
}

// Round 9
// 274.525 us; speedup vs baseline: 1.9362x; 1.9362x over previous
//
#include <hip/hip_runtime.h>
#include <math.h>

// Problem constants (from reference)
#define TT 10
#define SS 10
#define RR 2000
#define KK 100
#define OO 500
#define PP (TT*SS*RR)        // 200000 particles
#define NT16 12500           // 16-row tiles
#define NT 7                 // 7 N-tiles of 16 cols -> 112 padded assemblages
#define WAVES 16             // 1024-thread block, 1 block/CU -> 16 waves/CU
#define BLOCKT (WAVES*64)
#define NBLK 256
#define EPSF 1e-6f

typedef float        f32x4  __attribute__((ext_vector_type(4)));
typedef unsigned int u32x4  __attribute__((ext_vector_type(4)));
typedef __bf16       bf16x8 __attribute__((ext_vector_type(8)));

union BFU { bf16x8 v; u32x4 q; };

// XOR swizzle within a 1024B row (R1-verified conflict-light B layout)
__device__ __forceinline__ int swz(int row, int byteInRow) {
    return row * 1024 + (byteInRow ^ ((row & 7) << 4));
}

// ---------------------------------------------------------------------------
// Prep: theta = softmax -> out[1..50001); beta copy -> out[50001..);
// out[0] = 0; tile counter (d_ws) = 0.
// ---------------------------------------------------------------------------
__global__ __launch_bounds__(64) void mcspace_prep(
    const float* __restrict__ theta_params,
    const float* __restrict__ beta,
    float* __restrict__ out,
    unsigned* __restrict__ cnt)
{
    const int b  = blockIdx.x;
    const int ln = threadIdx.x;   // 64 lanes, one wave
    if (b < KK) {
        const float* tp = theta_params + b * OO;
        float x[8];
        #pragma unroll
        for (int j = 0; j < 8; ++j) {
            int o = ln + 64 * j;
            x[j] = (o < OO) ? tp[o] : -INFINITY;
        }
        float mx = x[0];
        #pragma unroll
        for (int j = 1; j < 8; ++j) mx = fmaxf(mx, x[j]);
        #pragma unroll
        for (int w = 1; w < 64; w <<= 1) mx = fmaxf(mx, __shfl_xor(mx, w));
        float e[8], sm = 0.f;
        #pragma unroll
        for (int j = 0; j < 8; ++j) { e[j] = __expf(x[j] - mx); sm += e[j]; }
        #pragma unroll
        for (int w = 1; w < 64; w <<= 1) sm += __shfl_xor(sm, w);
        const float inv = 1.f / sm;
        float* to = out + 1 + b * OO;
        #pragma unroll
        for (int j = 0; j < 8; ++j) {
            int o = ln + 64 * j;
            if (o < OO) to[o] = e[j] * inv;
        }
    } else {
        int idx = (b - KK) * 64 + ln;
        if (idx < KK * TT * SS) out[1 + KK * OO + idx] = beta[idx];
        if (b == KK && ln == 0) { out[0] = 0.f; cnt[0] = 0u; }
    }
}

// ---------------------------------------------------------------------------
// Main: R1 structure verbatim (B in LDS, direct A gather, 16 waves/CU) with
// the only change being a software-pipelined dynamic tile counter.
// ---------------------------------------------------------------------------
__global__ __launch_bounds__(BLOCKT) void mcspace_main(
    const float* __restrict__ counts,
    const float* __restrict__ theta_params,
    const float* __restrict__ beta,
    unsigned* __restrict__ cnt,
    float* __restrict__ out)
{
    __shared__ u32x4 ldsB[7168];   // logtheta bf16 [112][512], swizzled rows (112 KB)
    __shared__ float red[WAVES];
    char* ldsBytes = (char*)&ldsB[0];

    const int tid = threadIdx.x;
    const int wv  = tid >> 6;     // wave id 0..15
    const int ln  = tid & 63;
    const int lo  = ln & 15;
    const int g   = ln >> 4;
    const int kb  = g * 8;

    // ---- build logtheta bf16 [112][512] in LDS (each wave does 7 rows) ----
    for (int it = 0; it < 7; ++it) {
        const int row = wv + 16 * it;          // 0..111 (bijective)
        BFU w8; w8.q = (u32x4){0u, 0u, 0u, 0u};
        if (row < KK) {
            const float* tp = theta_params + row * OO;
            float x[8];
            #pragma unroll
            for (int j = 0; j < 8; ++j) {
                int o = ln * 8 + j;
                x[j] = (o < OO) ? tp[o] : -INFINITY;
            }
            float mx = x[0];
            #pragma unroll
            for (int j = 1; j < 8; ++j) mx = fmaxf(mx, x[j]);
            #pragma unroll
            for (int w = 1; w < 64; w <<= 1) mx = fmaxf(mx, __shfl_xor(mx, w));
            float e[8], sm = 0.f;
            #pragma unroll
            for (int j = 0; j < 8; ++j) { e[j] = __expf(x[j] - mx); sm += e[j]; }
            #pragma unroll
            for (int w = 1; w < 64; w <<= 1) sm += __shfl_xor(sm, w);
            const float inv = 1.f / sm;
            #pragma unroll
            for (int j = 0; j < 8; ++j)
                w8.v[j] = (__bf16)__logf(e[j] * inv + EPSF);  // log(theta + EPS)
        }
        *(u32x4*)(ldsBytes + swz(row, ln * 16)) = w8.q;
    }
    __syncthreads();

    float wacc = 0.f;

    // first tile id
    unsigned t = 0;
    if (ln == 0) t = atomicAdd(cnt, 1u);
    t = (unsigned)__shfl((int)t, 0);

    while (t < NT16) {
        // issue NEXT tile-id fetch now; consume after this tile's compute
        unsigned tn = 0;
        if (ln == 0) tn = atomicAdd(cnt, 1u);

        const int pbase = (int)t * 16;
        const int ts = pbase / RR;           // t*S + s (R divisible by 16)
        const float* rp = counts + (long)(pbase + lo) * OO;

        // beta for this tile's (t,s): lane lo owns column j = nt*16+lo
        float bet[NT];
        #pragma unroll
        for (int nt = 0; nt < NT; ++nt) {
            int j = nt * 16 + lo;
            bet[nt] = (j < KK) ? beta[j * (TT * SS) + ts] : 0.f;
        }

        f32x4 acc[NT];
        #pragma unroll
        for (int nt = 0; nt < NT; ++nt) acc[nt] = (f32x4){0.f, 0.f, 0.f, 0.f};

        // 15 full K-steps of 32 (k = 0..479)
        #pragma unroll 3
        for (int ko = 0; ko < 15; ++ko) {
            f32x4 a0 = *(const f32x4*)(rp + ko * 32 + kb);
            f32x4 a1 = *(const f32x4*)(rp + ko * 32 + kb + 4);
            BFU a;
            #pragma unroll
            for (int j = 0; j < 4; ++j) {
                a.v[j]     = (__bf16)a0[j];
                a.v[4 + j] = (__bf16)a1[j];
            }
            const int bb = ko * 64 + g * 16;
            #pragma unroll
            for (int nt = 0; nt < NT; ++nt) {
                BFU bv;
                bv.q = *(const u32x4*)(ldsBytes + swz(nt * 16 + lo, bb));
                acc[nt] = __builtin_amdgcn_mfma_f32_16x16x32_bf16(a.v, bv.v, acc[nt], 0, 0, 0);
            }
        }
        // remainder K-step: k = 480..511, only k < 500 valid (guard avoids OOB)
        {
            BFU a;
            #pragma unroll
            for (int j = 0; j < 8; ++j) {
                int k = 480 + kb + j;
                a.v[j] = (__bf16)((k < OO) ? rp[k] : 0.f);
            }
            const int bb = 15 * 64 + g * 16;
            #pragma unroll
            for (int nt = 0; nt < NT; ++nt) {
                BFU bv;
                bv.q = *(const u32x4*)(ldsBytes + swz(nt * 16 + lo, bb));
                acc[nt] = __builtin_amdgcn_mfma_f32_16x16x32_bf16(a.v, bv.v, acc[nt], 0, 0, 0);
            }
        }

        // ---- beta-weighted logsumexp (in-register, R1-verified layout) ----
        float mrow[4] = {-INFINITY, -INFINITY, -INFINITY, -INFINITY};
        #pragma unroll
        for (int nt = 0; nt < NT; ++nt) {
            const bool valid = (nt * 16 + lo) < KK;
            #pragma unroll
            for (int r = 0; r < 4; ++r) {
                float v = valid ? acc[nt][r] : -INFINITY;
                mrow[r] = fmaxf(mrow[r], v);
            }
        }
        #pragma unroll
        for (int w = 1; w < 16; w <<= 1) {
            #pragma unroll
            for (int r = 0; r < 4; ++r)
                mrow[r] = fmaxf(mrow[r], __shfl_xor(mrow[r], w));
        }
        float srow[4] = {0.f, 0.f, 0.f, 0.f};
        #pragma unroll
        for (int nt = 0; nt < NT; ++nt) {
            const bool valid = (nt * 16 + lo) < KK;
            #pragma unroll
            for (int r = 0; r < 4; ++r) {
                float v = valid ? (acc[nt][r] - mrow[r]) : -INFINITY;
                srow[r] += bet[nt] * __expf(v);
            }
        }
        #pragma unroll
        for (int w = 1; w < 16; w <<= 1) {
            #pragma unroll
            for (int r = 0; r < 4; ++r)
                srow[r] += __shfl_xor(srow[r], w);
        }
        if (lo == 0) {
            #pragma unroll
            for (int r = 0; r < 4; ++r)
                wacc += mrow[r] + __logf(srow[r] + EPSF);
        }

        // consume pipelined tile id
        t = (unsigned)__shfl((int)tn, 0);
    }

    // ---- deterministic block reduction, one atomic per block ----
    #pragma unroll
    for (int w = 1; w < 64; w <<= 1) wacc += __shfl_xor(wacc, w);
    if (ln == 0) red[wv] = wacc;
    __syncthreads();
    if (tid == 0) {
        float s = 0.f;
        #pragma unroll
        for (int i = 0; i < WAVES; ++i) s += red[i];
        atomicAdd(out, -s);   // elbo_loss = -loglik
    }
}

extern "C" void kernel_launch(void* const* d_in, const int* in_sizes, int n_in,
                              void* d_out, int out_size, void* d_ws, size_t ws_size,
                              hipStream_t stream)
{
    (void)in_sizes; (void)n_in; (void)ws_size; (void)out_size;
    const float* counts       = (const float*)d_in[0];
    const float* theta_params = (const float*)d_in[1];
    const float* beta         = (const float*)d_in[2];
    float* out    = (float*)d_out;
    unsigned* cnt = (unsigned*)d_ws;      // dynamic tile counter (zeroed by prep)

    // prep: 100 softmax rows + 157 beta-copy blocks (one wave each)
    mcspace_prep<<<dim3(KK + (KK * TT * SS + 63) / 64), dim3(64), 0, stream>>>(
        theta_params, beta, out, cnt);
    // main: 256 blocks x 16 waves (1 block/CU), dynamic pipelined tiles
    mcspace_main<<<dim3(NBLK), dim3(BLOCKT), 0, stream>>>(
        counts, theta_params, beta, cnt, out);
}